// Round 9
// baseline (826.417 us; speedup 1.0000x reference)
//
#include <hip/hip_runtime.h>
#include <math.h>

#define EMB 1024
#define NH 16
#define HD 64
#define NB 2
#define SQ 2048
#define BSQ (NB*SQ)
#define NG 16
#define OUT0 ((size_t)BSQ*EMB)

typedef __attribute__((ext_vector_type(8))) short bf16x8;
typedef __attribute__((ext_vector_type(4))) float f32x4;

#define C_LOG2E_8 0.18033688011112042f   // log2(e)/8

__device__ __forceinline__ short f2bf(float x){
    unsigned u = __float_as_uint(x);
    u += 0x7fff + ((u >> 16) & 1);     // RNE
    return (short)(u >> 16);
}
__device__ __forceinline__ float bf2f(short h){
    return __uint_as_float(((unsigned)(unsigned short)h) << 16);
}

// ---------------------------------------------------------------------------
// fused prep: z<4 -> dequant weight quadrant z (hi always, lo for q,k);
//             z>=4 -> split X quarter (z-4) into bf16 hi/lo
// ---------------------------------------------------------------------------
__global__ __launch_bounds__(256) void k_prep(
        const float* __restrict__ hs,
        const int* qq, const float* qs, const float* qz,
        const int* kq, const float* ks, const float* kz,
        const int* vq, const float* vs, const float* vz,
        const int* oq, const float* os, const float* oz,
        short* __restrict__ Wh, short* __restrict__ Wl,
        short* __restrict__ Xh, short* __restrict__ Xl)
{
    int z = blockIdx.z;
    int idx = (blockIdx.x*256 + threadIdx.x)*8;
    alignas(16) short hv[8];
    alignas(16) short lv[8];
    if (z < 4) {
        const int*   qw = z==0?qq : z==1?kq : z==2?vq : oq;
        const float* sc = z==0?qs : z==1?ks : z==2?vs : os;
        const float* zp = z==0?qz : z==1?kz : z==2?vz : oz;
        size_t base = (size_t)z*EMB*EMB;
        int4 a = *(const int4*)(qw + idx);
        int4 b = *(const int4*)(qw + idx + 4);
        int o = idx >> 10, g = (idx & 1023) >> 6;
        float s = sc[o*NG + g], zv = zp[o*NG + g];
        int qv[8] = {a.x,a.y,a.z,a.w,b.x,b.y,b.z,b.w};
        #pragma unroll
        for (int j = 0; j < 8; ++j) {
            float wv = ((float)qv[j] - zv)*s;
            short h = f2bf(wv); hv[j] = h;
            lv[j] = f2bf(wv - bf2f(h));
        }
        *(bf16x8*)(Wh + base + idx) = *(const bf16x8*)hv;
        if (z < 2)
            *(bf16x8*)(Wl + base + idx) = *(const bf16x8*)lv;
    } else {
        size_t off = (size_t)(z - 4)*((size_t)BSQ/4*EMB) + idx;
        float4 a = *(const float4*)(hs + off);
        float4 b = *(const float4*)(hs + off + 4);
        float xv[8] = {a.x,a.y,a.z,a.w,b.x,b.y,b.z,b.w};
        #pragma unroll
        for (int j = 0; j < 8; ++j) {
            short h = f2bf(xv[j]); hv[j] = h;
            lv[j] = f2bf(xv[j] - bf2f(h));
        }
        *(bf16x8*)(Xh + off) = *(const bf16x8*)hv;
        *(bf16x8*)(Xl + off) = *(const bf16x8*)lv;
    }
}

// ---------------------------------------------------------------------------
// bf16 MFMA GEMM body: C[4096,1024] = A[4096,1024] * B[1024,1024]^T + bias
// TERMS=3: hh+hl+lh split.  TERMS=1: plain bf16.
// EPI: 0 = bf16 hi/lo pair; 2 = fp32 (nt); 3 = transposed bf16 -> Vt[z][d][s]
// 128x128 tile, BK=32, 4 waves (2x2).
// ---------------------------------------------------------------------------
template<int TERMS, int EPI>
__device__ __forceinline__ void proj_body(
        const short* __restrict__ Ahg, const short* __restrict__ Alg,
        const short* __restrict__ Bhg, const short* __restrict__ Blg,
        const float* __restrict__ bias,
        short* __restrict__ outH, short* __restrict__ outL,
        float* __restrict__ outF,
        int bx, int by)
{
    constexpr bool SPL = (TERMS > 1);
    constexpr int LSTR = 40;
    constexpr int MSZ  = 128*LSTR*(SPL?2:1);
    constexpr int STAGE = 2*MSZ;
    constexpr int TSH  = (EPI == 3) ? 128*136 : 0;
    constexpr int LDSN = (STAGE > TSH) ? STAGE : TSH;
    __shared__ short lds[LDSN];
    short* As  = lds;
    short* Bs  = lds + MSZ;
    short* Asl = As + 128*LSTR;
    short* Bsl = Bs + 128*LSTR;

    const int tid = threadIdx.x;
    const int l = tid & 63, w = tid >> 6;
    const int lrow = l & 15, lq = l >> 4;
    const int wr = w >> 1, wc = w & 1;
    const int m0 = by*128, n0 = bx*128;
    const int r = tid >> 1, kh = (tid & 1)*16;

    f32x4 acc[4][4] = {};

    for (int k0 = 0; k0 < EMB; k0 += 32) {
        const short* as = Ahg + (size_t)(m0 + r)*EMB + k0 + kh;
        bf16x8 a0 = *(const bf16x8*)as;
        bf16x8 a1 = *(const bf16x8*)(as + 8);
        const short* bs = Bhg + (size_t)(n0 + r)*EMB + k0 + kh;
        bf16x8 b0 = *(const bf16x8*)bs;
        bf16x8 b1 = *(const bf16x8*)(bs + 8);
        bf16x8 a2{}, a3{}, b2{}, b3{};
        if constexpr (SPL) {
            const short* as2 = Alg + (size_t)(m0 + r)*EMB + k0 + kh;
            a2 = *(const bf16x8*)as2; a3 = *(const bf16x8*)(as2 + 8);
            const short* bs2 = Blg + (size_t)(n0 + r)*EMB + k0 + kh;
            b2 = *(const bf16x8*)bs2; b3 = *(const bf16x8*)(bs2 + 8);
        }
        __syncthreads();
        *(bf16x8*)(As + r*LSTR + kh)     = a0;
        *(bf16x8*)(As + r*LSTR + kh + 8) = a1;
        *(bf16x8*)(Bs + r*LSTR + kh)     = b0;
        *(bf16x8*)(Bs + r*LSTR + kh + 8) = b1;
        if constexpr (SPL) {
            *(bf16x8*)(Asl + r*LSTR + kh)     = a2;
            *(bf16x8*)(Asl + r*LSTR + kh + 8) = a3;
            *(bf16x8*)(Bsl + r*LSTR + kh)     = b2;
            *(bf16x8*)(Bsl + r*LSTR + kh + 8) = b3;
        }
        __syncthreads();

        bf16x8 aH[4], aL[4], bH[4], bL[4];
        #pragma unroll
        for (int i = 0; i < 4; ++i) {
            aH[i] = *(const bf16x8*)(As + (wr*64 + i*16 + lrow)*LSTR + lq*8);
            if constexpr (SPL) aL[i] = *(const bf16x8*)(Asl + (wr*64 + i*16 + lrow)*LSTR + lq*8);
        }
        #pragma unroll
        for (int j = 0; j < 4; ++j) {
            bH[j] = *(const bf16x8*)(Bs + (wc*64 + j*16 + lrow)*LSTR + lq*8);
            if constexpr (SPL) bL[j] = *(const bf16x8*)(Bsl + (wc*64 + j*16 + lrow)*LSTR + lq*8);
        }
        #pragma unroll
        for (int i = 0; i < 4; ++i)
            #pragma unroll
            for (int j = 0; j < 4; ++j) {
                acc[i][j] = __builtin_amdgcn_mfma_f32_16x16x32_bf16(aH[i], bH[j], acc[i][j], 0, 0, 0);
                if constexpr (SPL) {
                    acc[i][j] = __builtin_amdgcn_mfma_f32_16x16x32_bf16(aH[i], bL[j], acc[i][j], 0, 0, 0);
                    acc[i][j] = __builtin_amdgcn_mfma_f32_16x16x32_bf16(aL[i], bH[j], acc[i][j], 0, 0, 0);
                }
            }
    }

    if constexpr (EPI == 3) {
        // transpose through LDS, write Vt[z][d][s] coalesced along s
        __syncthreads();
        #pragma unroll
        for (int i = 0; i < 4; ++i) {
            int rl = wr*64 + i*16 + lq*4;
            #pragma unroll
            for (int j = 0; j < 4; ++j) {
                int cl = wc*64 + j*16 + lrow;
                float bv = bias[n0 + cl];
                #pragma unroll
                for (int rr = 0; rr < 4; ++rr)
                    lds[cl*136 + rl + rr] = f2bf(acc[i][j][rr] + bv);
            }
        }
        __syncthreads();
        int c = tid >> 1, hf = (tid & 1)*64;
        int gc = n0 + c;
        int z2 = (m0 >> 11)*16 + (gc >> 6);
        int d = gc & 63;
        short* dst = outH + ((size_t)z2*HD + d)*SQ + (m0 & (SQ-1)) + hf;
        #pragma unroll
        for (int u = 0; u < 8; ++u)
            *(bf16x8*)(dst + u*8) = *(const bf16x8*)(lds + c*136 + hf + u*8);
        return;
    }

    #pragma unroll
    for (int i = 0; i < 4; ++i) {
        int rb = m0 + wr*64 + i*16 + lq*4;
        #pragma unroll
        for (int j = 0; j < 4; ++j) {
            int cb = n0 + wc*64 + j*16 + lrow;
            float bv = bias[cb];
            #pragma unroll
            for (int rr = 0; rr < 4; ++rr) {
                float y = acc[i][j][rr] + bv;
                size_t off = (size_t)(rb + rr)*EMB + cb;
                if constexpr (EPI == 0) {
                    short hh = f2bf(y);
                    outH[off] = hh;
                    outL[off] = f2bf(y - bf2f(hh));
                } else {
                    __builtin_nontemporal_store(y, outF + off);
                }
            }
        }
    }
}

// Q, K (3-term, hi/lo out) and V (1-term, transposed out) fused over grid.z
__global__ __launch_bounds__(256, 2) void k_projqkv(
        const short* __restrict__ Xh, const short* __restrict__ Xl,
        const short* __restrict__ Wh, const short* __restrict__ Wl,
        const float* bq, const float* bk, const float* bv,
        short* Qh, short* Ql, short* Kh, short* Kl, short* Vt)
{
    const size_t WSZ = (size_t)EMB*EMB;
    int z = blockIdx.z;
    if (z < 2)
        proj_body<3,0>(Xh, Xl, Wh + (size_t)z*WSZ, Wl + (size_t)z*WSZ,
                       z ? bk : bq, z ? Kh : Qh, z ? Kl : Ql, nullptr,
                       blockIdx.x, blockIdx.y);
    else
        proj_body<1,3>(Xh, nullptr, Wh + 2*WSZ, nullptr, bv, Vt, nullptr, nullptr,
                       blockIdx.x, blockIdx.y);
}

__global__ __launch_bounds__(256, 2) void k_projo(
        const short* __restrict__ AO, const short* __restrict__ Wh,
        const float* bo, float* out)
{
    proj_body<1,2>(AO, nullptr, Wh, nullptr, bo, nullptr, nullptr, out,
                   blockIdx.x, blockIdx.y);
}

// ---------------------------------------------------------------------------
// attention, two passes over an identical score computation, exp2 domain.
// scores s2 = acc * C_LOG2E_8;  p = 2^(s2 - M),  M = m2 + log2(l).
// PASS1: lane-local online (m2,l); butterfly merge; write M per row.
// PASS2: p via single exp2; P (bf16) -> LDS -> coalesced fp32 attn write + P*V.
// ---------------------------------------------------------------------------
template<int PASS>
__global__ __launch_bounds__(256, (PASS==1) ? 4 : 2) void k_attn(
        const short* __restrict__ Qh, const short* __restrict__ Ql,
        const short* __restrict__ Kh, const short* __restrict__ Kl,
        const short* __restrict__ Vt,
        float* __restrict__ ml,
        float* __restrict__ attn,
        short* __restrict__ AO)
{
    constexpr int LSTR = 72;                 // 64 + 8 pad
    // PASS1: Q staged through kbuf (exactly 128*LSTR shorts); no qbuf.
    __shared__ short qbuf[(PASS==2) ? 128*LSTR : 8];
    __shared__ short kbuf[64*LSTR*2];        // hi | lo
    __shared__ short vbuf[(PASS==2) ? 64*LSTR : 8];
    constexpr int KOFF = 64*LSTR;

    const int tid = threadIdx.x;
    const int l = tid & 63, w = tid >> 6;
    const int lrow = l & 15, lq = l >> 4;
    const int z = blockIdx.y, b = z >> 4, h = z & 15;
    const int i0 = blockIdx.x*128;
    const size_t qrow0 = (size_t)(b*SQ + i0);
    const size_t zbase = (size_t)z*SQ*SQ;

    const int rs = tid >> 1, kh0 = (tid & 1)*32;
    short* qstage = (PASS == 2) ? (short*)qbuf : (short*)kbuf;
    bf16x8 aH[2][2], aL[2][2];
    {
        const short* qh = Qh + (qrow0 + rs)*EMB + h*HD + kh0;
        #pragma unroll
        for (int u = 0; u < 4; ++u)
            *(bf16x8*)(qstage + rs*LSTR + kh0 + u*8) = *(const bf16x8*)(qh + u*8);
        __syncthreads();
        #pragma unroll
        for (int i = 0; i < 2; ++i)
            #pragma unroll
            for (int ks = 0; ks < 2; ++ks)
                aH[i][ks] = *(const bf16x8*)(qstage + (w*32 + i*16 + lrow)*LSTR + ks*32 + lq*8);
        __syncthreads();
        const short* ql = Ql + (qrow0 + rs)*EMB + h*HD + kh0;
        #pragma unroll
        for (int u = 0; u < 4; ++u)
            *(bf16x8*)(qstage + rs*LSTR + kh0 + u*8) = *(const bf16x8*)(ql + u*8);
        __syncthreads();
        #pragma unroll
        for (int i = 0; i < 2; ++i)
            #pragma unroll
            for (int ks = 0; ks < 2; ++ks)
                aL[i][ks] = *(const bf16x8*)(qstage + (w*32 + i*16 + lrow)*LSTR + ks*32 + lq*8);
    }

    // PASS1: running (m2, l) in exp2 domain.  PASS2: M = m2 + log2(l).
    float m_st[2][4], l_st[2][4];
    #pragma unroll
    for (int i = 0; i < 2; ++i)
        #pragma unroll
        for (int rr = 0; rr < 4; ++rr) {
            if constexpr (PASS == 1) {
                m_st[i][rr] = -INFINITY; l_st[i][rr] = 0.f;
            } else {
                int row = i0 + w*32 + i*16 + lq*4 + rr;
                m_st[i][rr] = ml[(size_t)z*SQ + row];
            }
        }

    f32x4 oa[2][4] = {};

    for (int j0 = 0; j0 < SQ; j0 += 64) {
        int c = tid >> 2, kh2 = (tid & 3)*16;
        const short* khp = Kh + (size_t)(b*SQ + j0 + c)*EMB + h*HD + kh2;
        const short* klp = Kl + (size_t)(b*SQ + j0 + c)*EMB + h*HD + kh2;
        bf16x8 k0a = *(const bf16x8*)khp;
        bf16x8 k0b = *(const bf16x8*)(khp + 8);
        bf16x8 k1a = *(const bf16x8*)klp;
        bf16x8 k1b = *(const bf16x8*)(klp + 8);
        bf16x8 va{}, vb{};
        if constexpr (PASS == 2) {
            const short* vp = Vt + ((size_t)z*HD + c)*SQ + j0 + kh2;
            va = *(const bf16x8*)vp;
            vb = *(const bf16x8*)(vp + 8);
        }
        __syncthreads();
        *(bf16x8*)(kbuf + c*LSTR + kh2)            = k0a;
        *(bf16x8*)(kbuf + c*LSTR + kh2 + 8)        = k0b;
        *(bf16x8*)(kbuf + KOFF + c*LSTR + kh2)     = k1a;
        *(bf16x8*)(kbuf + KOFF + c*LSTR + kh2 + 8) = k1b;
        if constexpr (PASS == 2) {
            *(bf16x8*)(vbuf + c*LSTR + kh2)     = va;
            *(bf16x8*)(vbuf + c*LSTR + kh2 + 8) = vb;
        }
        __syncthreads();

        f32x4 acc[2][4] = {};
        #pragma unroll
        for (int ks = 0; ks < 2; ++ks) {
            bf16x8 bH[4], bL[4];
            #pragma unroll
            for (int jj = 0; jj < 4; ++jj) {
                bH[jj] = *(const bf16x8*)(kbuf + (jj*16 + lrow)*LSTR + ks*32 + lq*8);
                bL[jj] = *(const bf16x8*)(kbuf + KOFF + (jj*16 + lrow)*LSTR + ks*32 + lq*8);
            }
            #pragma unroll
            for (int i = 0; i < 2; ++i)
                #pragma unroll
                for (int jj = 0; jj < 4; ++jj) {
                    acc[i][jj] = __builtin_amdgcn_mfma_f32_16x16x32_bf16(aH[i][ks], bH[jj], acc[i][jj], 0, 0, 0);
                    acc[i][jj] = __builtin_amdgcn_mfma_f32_16x16x32_bf16(aH[i][ks], bL[jj], acc[i][jj], 0, 0, 0);
                    acc[i][jj] = __builtin_amdgcn_mfma_f32_16x16x32_bf16(aL[i][ks], bH[jj], acc[i][jj], 0, 0, 0);
                }
        }

        #pragma unroll
        for (int i = 0; i < 2; ++i)
            #pragma unroll
            for (int rr = 0; rr < 4; ++rr) {
                if constexpr (PASS == 1) {
                    float s0 = acc[i][0][rr]*C_LOG2E_8;
                    float s1 = acc[i][1][rr]*C_LOG2E_8;
                    float s2 = acc[i][2][rr]*C_LOG2E_8;
                    float s3 = acc[i][3][rr]*C_LOG2E_8;
                    float tm = fmaxf(fmaxf(s0, s1), fmaxf(s2, s3));
                    float mo = m_st[i][rr];
                    float mn = fmaxf(mo, tm);
                    l_st[i][rr] = l_st[i][rr]*exp2f(mo - mn)
                                + exp2f(s0 - mn) + exp2f(s1 - mn)
                                + exp2f(s2 - mn) + exp2f(s3 - mn);
                    m_st[i][rr] = mn;
                } else {
                    #pragma unroll
                    for (int jj = 0; jj < 4; ++jj) {
                        float p = exp2f(acc[i][jj][rr]*C_LOG2E_8 - m_st[i][rr]);
                        qbuf[(w*32 + i*16 + lq*4 + rr)*LSTR + jj*16 + lrow] = f2bf(p);
                    }
                }
            }

        if constexpr (PASS == 2) {
            // wave-private: write the wave's 32x64 P tile to attn, coalesced
            #pragma unroll
            for (int ri = 0; ri < 8; ++ri) {
                int rl = w*32 + ri*4 + lq;
                const short* src = qbuf + rl*LSTR + lrow*4;
                short4 p4 = *(const short4*)src;
                f32x4 f;
                f[0] = bf2f(p4.x); f[1] = bf2f(p4.y);
                f[2] = bf2f(p4.z); f[3] = bf2f(p4.w);
                __builtin_nontemporal_store(f,
                    (f32x4*)(attn + zbase + (size_t)(i0 + rl)*SQ + j0 + lrow*4));
            }
            // P*V (qbuf rows wave-private)
            #pragma unroll
            for (int ks = 0; ks < 2; ++ks) {
                bf16x8 ap[2], bv[4];
                #pragma unroll
                for (int i = 0; i < 2; ++i)
                    ap[i] = *(const bf16x8*)(qbuf + (w*32 + i*16 + lrow)*LSTR + ks*32 + lq*8);
                #pragma unroll
                for (int nd = 0; nd < 4; ++nd)
                    bv[nd] = *(const bf16x8*)(vbuf + (nd*16 + lrow)*LSTR + ks*32 + lq*8);
                #pragma unroll
                for (int i = 0; i < 2; ++i)
                    #pragma unroll
                    for (int nd = 0; nd < 4; ++nd)
                        oa[i][nd] = __builtin_amdgcn_mfma_f32_16x16x32_bf16(ap[i], bv[nd], oa[i][nd], 0, 0, 0);
            }
        }
    }

    if constexpr (PASS == 1) {
        #pragma unroll
        for (int i = 0; i < 2; ++i)
            #pragma unroll
            for (int rr = 0; rr < 4; ++rr) {
                float m = m_st[i][rr], lv = l_st[i][rr];
                #pragma unroll
                for (int off = 1; off < 16; off <<= 1) {
                    float m2 = __shfl_xor(m, off);
                    float l2 = __shfl_xor(lv, off);
                    float mn = fmaxf(m, m2);
                    lv = lv*exp2f(m - mn) + l2*exp2f(m2 - mn);
                    m = mn;
                }
                if (lrow == 0) {
                    int row = i0 + w*32 + i*16 + lq*4 + rr;
                    ml[(size_t)z*SQ + row] = m + log2f(lv);
                }
            }
    } else {
        #pragma unroll
        for (int i = 0; i < 2; ++i)
            #pragma unroll
            for (int rr = 0; rr < 4; ++rr) {
                int row = i0 + w*32 + i*16 + lq*4 + rr;
                #pragma unroll
                for (int nd = 0; nd < 4; ++nd)
                    AO[(size_t)(b*SQ + row)*EMB + h*HD + nd*16 + lrow] = f2bf(oa[i][nd][rr]);
            }
    }
}

// ---------------------------------------------------------------------------
extern "C" void kernel_launch(void* const* d_in, const int* in_sizes, int n_in,
                              void* d_out, int out_size, void* d_ws, size_t ws_size,
                              hipStream_t stream)
{
    const float* hs   = (const float*)d_in[0];
    const int*   q_qw = (const int*)  d_in[1];
    const float* q_sc = (const float*)d_in[2];
    const float* q_zp = (const float*)d_in[3];
    const float* q_b  = (const float*)d_in[4];
    const int*   k_qw = (const int*)  d_in[5];
    const float* k_sc = (const float*)d_in[6];
    const float* k_zp = (const float*)d_in[7];
    const float* k_b  = (const float*)d_in[8];
    const int*   v_qw = (const int*)  d_in[9];
    const float* v_sc = (const float*)d_in[10];
    const float* v_zp = (const float*)d_in[11];
    const float* v_b  = (const float*)d_in[12];
    const int*   o_qw = (const int*)  d_in[13];
    const float* o_sc = (const float*)d_in[14];
    const float* o_zp = (const float*)d_in[15];
    const float* o_b  = (const float*)d_in[16];

    float* out  = (float*)d_out;
    float* attn = out + OUT0;

    // ws layout (60.5 MB <= 64 MB):
    //   ml | Wh: 4MW | Wl: 2MW (q,k) | Xh (->AO) | Xl (->Vt) | Qh | Ql | Kh | Kl
    const size_t WSZ = (size_t)EMB*EMB;
    const size_t TSZ = (size_t)BSQ*EMB;
    float* ml = (float*)d_ws;
    short* Wh = (short*)(ml + 2*(size_t)NB*NH*SQ);
    short* Wl = Wh + 4*WSZ;
    short* Xh = Wl + 2*WSZ;
    short* Xl = Xh + TSZ;
    short* Qh = Xl + TSZ;
    short* Ql = Qh + TSZ;
    short* Kh = Ql + TSZ;
    short* Kl = Kh + TSZ;
    short* Vt = Xl;   // overlay: Xl dead after K projection
    short* AO = Xh;   // overlay: Xh dead after V projection

    dim3 blk(256);

    k_prep<<<dim3(512, 1, 8), blk, 0, stream>>>(
        hs,
        q_qw, q_sc, q_zp, k_qw, k_sc, k_zp,
        v_qw, v_sc, v_zp, o_qw, o_sc, o_zp,
        Wh, Wl, Xh, Xl);

    k_projqkv<<<dim3(8, 32, 3), blk, 0, stream>>>(
        Xh, Xl, Wh, Wl, q_b, k_b, v_b, Qh, Ql, Kh, Kl, Vt);

    k_attn<1><<<dim3(16, 32), blk, 0, stream>>>(Qh, Ql, Kh, Kl, nullptr, ml, nullptr, nullptr);
    k_attn<2><<<dim3(16, 32), blk, 0, stream>>>(Qh, Ql, Kh, Kl, Vt, ml, attn, AO);

    k_projo<<<dim3(8, 32), blk, 0, stream>>>(AO, Wh + 3*WSZ, o_b, out);
}

// Round 10
// 826.272 us; speedup vs baseline: 1.0002x; 1.0002x over previous
//
#include <hip/hip_runtime.h>
#include <math.h>

#define EMB 1024
#define NH 16
#define HD 64
#define NB 2
#define SQ 2048
#define BSQ (NB*SQ)
#define NG 16
#define OUT0 ((size_t)BSQ*EMB)

typedef __attribute__((ext_vector_type(8))) short bf16x8;
typedef __attribute__((ext_vector_type(4))) float f32x4;

#define C_LOG2E_8 0.18033688011112042f   // log2(e)/8, folded into Q projection

__device__ __forceinline__ short f2bf(float x){
    unsigned u = __float_as_uint(x);
    u += 0x7fff + ((u >> 16) & 1);     // RNE
    return (short)(u >> 16);
}
__device__ __forceinline__ float bf2f(short h){
    return __uint_as_float(((unsigned)(unsigned short)h) << 16);
}

// ---------------------------------------------------------------------------
// fused prep: z<4 -> dequant weight quadrant z (hi always, lo for q,k);
//             z>=4 -> split X quarter (z-4) into bf16 hi/lo
// ---------------------------------------------------------------------------
__global__ __launch_bounds__(256) void k_prep(
        const float* __restrict__ hs,
        const int* qq, const float* qs, const float* qz,
        const int* kq, const float* ks, const float* kz,
        const int* vq, const float* vs, const float* vz,
        const int* oq, const float* os, const float* oz,
        short* __restrict__ Wh, short* __restrict__ Wl,
        short* __restrict__ Xh, short* __restrict__ Xl)
{
    int z = blockIdx.z;
    int idx = (blockIdx.x*256 + threadIdx.x)*8;
    alignas(16) short hv[8];
    alignas(16) short lv[8];
    if (z < 4) {
        const int*   qw = z==0?qq : z==1?kq : z==2?vq : oq;
        const float* sc = z==0?qs : z==1?ks : z==2?vs : os;
        const float* zp = z==0?qz : z==1?kz : z==2?vz : oz;
        size_t base = (size_t)z*EMB*EMB;
        int4 a = *(const int4*)(qw + idx);
        int4 b = *(const int4*)(qw + idx + 4);
        int o = idx >> 10, g = (idx & 1023) >> 6;
        float s = sc[o*NG + g], zv = zp[o*NG + g];
        int qv[8] = {a.x,a.y,a.z,a.w,b.x,b.y,b.z,b.w};
        #pragma unroll
        for (int j = 0; j < 8; ++j) {
            float wv = ((float)qv[j] - zv)*s;
            short h = f2bf(wv); hv[j] = h;
            lv[j] = f2bf(wv - bf2f(h));
        }
        *(bf16x8*)(Wh + base + idx) = *(const bf16x8*)hv;
        if (z < 2)
            *(bf16x8*)(Wl + base + idx) = *(const bf16x8*)lv;
    } else {
        size_t off = (size_t)(z - 4)*((size_t)BSQ/4*EMB) + idx;
        float4 a = *(const float4*)(hs + off);
        float4 b = *(const float4*)(hs + off + 4);
        float xv[8] = {a.x,a.y,a.z,a.w,b.x,b.y,b.z,b.w};
        #pragma unroll
        for (int j = 0; j < 8; ++j) {
            short h = f2bf(xv[j]); hv[j] = h;
            lv[j] = f2bf(xv[j] - bf2f(h));
        }
        *(bf16x8*)(Xh + off) = *(const bf16x8*)hv;
        *(bf16x8*)(Xl + off) = *(const bf16x8*)lv;
    }
}

// ---------------------------------------------------------------------------
// bf16 MFMA GEMM body: C[4096,1024] = A[4096,1024] * B[1024,1024]^T + bias
// TERMS=3: hh+hl+lh split.  TERMS=1: plain bf16.
// EPI: 0 = bf16 hi/lo pair (scaled by oscale); 2 = fp32 (nt);
//      3 = transposed bf16 -> Vt[z][d][s]
// 128x128 tile, BK=32, 4 waves (2x2).
// ---------------------------------------------------------------------------
template<int TERMS, int EPI>
__device__ __forceinline__ void proj_body(
        const short* __restrict__ Ahg, const short* __restrict__ Alg,
        const short* __restrict__ Bhg, const short* __restrict__ Blg,
        const float* __restrict__ bias,
        short* __restrict__ outH, short* __restrict__ outL,
        float* __restrict__ outF,
        int bx, int by, float oscale)
{
    constexpr bool SPL = (TERMS > 1);
    constexpr int LSTR = 40;
    constexpr int MSZ  = 128*LSTR*(SPL?2:1);
    constexpr int STAGE = 2*MSZ;
    constexpr int TSH  = (EPI == 3) ? 128*136 : 0;
    constexpr int LDSN = (STAGE > TSH) ? STAGE : TSH;
    __shared__ short lds[LDSN];
    short* As  = lds;
    short* Bs  = lds + MSZ;
    short* Asl = As + 128*LSTR;
    short* Bsl = Bs + 128*LSTR;

    const int tid = threadIdx.x;
    const int l = tid & 63, w = tid >> 6;
    const int lrow = l & 15, lq = l >> 4;
    const int wr = w >> 1, wc = w & 1;
    const int m0 = by*128, n0 = bx*128;
    const int r = tid >> 1, kh = (tid & 1)*16;

    f32x4 acc[4][4] = {};

    for (int k0 = 0; k0 < EMB; k0 += 32) {
        const short* as = Ahg + (size_t)(m0 + r)*EMB + k0 + kh;
        bf16x8 a0 = *(const bf16x8*)as;
        bf16x8 a1 = *(const bf16x8*)(as + 8);
        const short* bs = Bhg + (size_t)(n0 + r)*EMB + k0 + kh;
        bf16x8 b0 = *(const bf16x8*)bs;
        bf16x8 b1 = *(const bf16x8*)(bs + 8);
        bf16x8 a2{}, a3{}, b2{}, b3{};
        if constexpr (SPL) {
            const short* as2 = Alg + (size_t)(m0 + r)*EMB + k0 + kh;
            a2 = *(const bf16x8*)as2; a3 = *(const bf16x8*)(as2 + 8);
            const short* bs2 = Blg + (size_t)(n0 + r)*EMB + k0 + kh;
            b2 = *(const bf16x8*)bs2; b3 = *(const bf16x8*)(bs2 + 8);
        }
        __syncthreads();
        *(bf16x8*)(As + r*LSTR + kh)     = a0;
        *(bf16x8*)(As + r*LSTR + kh + 8) = a1;
        *(bf16x8*)(Bs + r*LSTR + kh)     = b0;
        *(bf16x8*)(Bs + r*LSTR + kh + 8) = b1;
        if constexpr (SPL) {
            *(bf16x8*)(Asl + r*LSTR + kh)     = a2;
            *(bf16x8*)(Asl + r*LSTR + kh + 8) = a3;
            *(bf16x8*)(Bsl + r*LSTR + kh)     = b2;
            *(bf16x8*)(Bsl + r*LSTR + kh + 8) = b3;
        }
        __syncthreads();

        bf16x8 aH[4], aL[4], bH[4], bL[4];
        #pragma unroll
        for (int i = 0; i < 4; ++i) {
            aH[i] = *(const bf16x8*)(As + (wr*64 + i*16 + lrow)*LSTR + lq*8);
            if constexpr (SPL) aL[i] = *(const bf16x8*)(Asl + (wr*64 + i*16 + lrow)*LSTR + lq*8);
        }
        #pragma unroll
        for (int j = 0; j < 4; ++j) {
            bH[j] = *(const bf16x8*)(Bs + (wc*64 + j*16 + lrow)*LSTR + lq*8);
            if constexpr (SPL) bL[j] = *(const bf16x8*)(Bsl + (wc*64 + j*16 + lrow)*LSTR + lq*8);
        }
        #pragma unroll
        for (int i = 0; i < 4; ++i)
            #pragma unroll
            for (int j = 0; j < 4; ++j) {
                acc[i][j] = __builtin_amdgcn_mfma_f32_16x16x32_bf16(aH[i], bH[j], acc[i][j], 0, 0, 0);
                if constexpr (SPL) {
                    acc[i][j] = __builtin_amdgcn_mfma_f32_16x16x32_bf16(aH[i], bL[j], acc[i][j], 0, 0, 0);
                    acc[i][j] = __builtin_amdgcn_mfma_f32_16x16x32_bf16(aL[i], bH[j], acc[i][j], 0, 0, 0);
                }
            }
    }

    if constexpr (EPI == 3) {
        // transpose through LDS, write Vt[z][d][s] coalesced along s
        __syncthreads();
        #pragma unroll
        for (int i = 0; i < 4; ++i) {
            int rl = wr*64 + i*16 + lq*4;
            #pragma unroll
            for (int j = 0; j < 4; ++j) {
                int cl = wc*64 + j*16 + lrow;
                float bv = bias[n0 + cl];
                #pragma unroll
                for (int rr = 0; rr < 4; ++rr)
                    lds[cl*136 + rl + rr] = f2bf(acc[i][j][rr] + bv);
            }
        }
        __syncthreads();
        int c = tid >> 1, hf = (tid & 1)*64;
        int gc = n0 + c;
        int z2 = (m0 >> 11)*16 + (gc >> 6);
        int d = gc & 63;
        short* dst = outH + ((size_t)z2*HD + d)*SQ + (m0 & (SQ-1)) + hf;
        #pragma unroll
        for (int u = 0; u < 8; ++u)
            *(bf16x8*)(dst + u*8) = *(const bf16x8*)(lds + c*136 + hf + u*8);
        return;
    }

    #pragma unroll
    for (int i = 0; i < 4; ++i) {
        int rb = m0 + wr*64 + i*16 + lq*4;
        #pragma unroll
        for (int j = 0; j < 4; ++j) {
            int cb = n0 + wc*64 + j*16 + lrow;
            float bv = bias[cb];
            #pragma unroll
            for (int rr = 0; rr < 4; ++rr) {
                float y = acc[i][j][rr] + bv;
                size_t off = (size_t)(rb + rr)*EMB + cb;
                if constexpr (EPI == 0) {
                    y *= oscale;
                    short hh = f2bf(y);
                    outH[off] = hh;
                    outL[off] = f2bf(y - bf2f(hh));
                } else {
                    __builtin_nontemporal_store(y, outF + off);
                }
            }
        }
    }
}

// Q (scaled by log2(e)/8), K (3-term, hi/lo out), V (1-term, transposed) via grid.z
__global__ __launch_bounds__(256, 2) void k_projqkv(
        const short* __restrict__ Xh, const short* __restrict__ Xl,
        const short* __restrict__ Wh, const short* __restrict__ Wl,
        const float* bq, const float* bk, const float* bv,
        short* Qh, short* Ql, short* Kh, short* Kl, short* Vt)
{
    const size_t WSZ = (size_t)EMB*EMB;
    int z = blockIdx.z;
    if (z < 2)
        proj_body<3,0>(Xh, Xl, Wh + (size_t)z*WSZ, Wl + (size_t)z*WSZ,
                       z ? bk : bq, z ? Kh : Qh, z ? Kl : Ql, nullptr,
                       blockIdx.x, blockIdx.y, z ? 1.0f : C_LOG2E_8);
    else
        proj_body<1,3>(Xh, nullptr, Wh + 2*WSZ, nullptr, bv, Vt, nullptr, nullptr,
                       blockIdx.x, blockIdx.y, 1.0f);
}

__global__ __launch_bounds__(256, 2) void k_projo(
        const short* __restrict__ AO, const short* __restrict__ Wh,
        const float* bo, float* out)
{
    proj_body<1,2>(AO, nullptr, Wh, nullptr, bo, nullptr, nullptr, out,
                   blockIdx.x, blockIdx.y, 1.0f);
}

// ---------------------------------------------------------------------------
// attention, two passes over an identical score computation, exp2 domain.
// Q pre-scaled by log2(e)/8, so score s2 = acc directly; p = 2^(s2 - M),
// M = m2 + log2(l).
// PASS1: lane-local online (m2,l); butterfly merge; write M per row.
// PASS2: p via single exp2; P (bf16) -> LDS -> coalesced fp32 attn write + P*V.
// ---------------------------------------------------------------------------
template<int PASS>
__global__ __launch_bounds__(256, (PASS==1) ? 3 : 2) void k_attn(
        const short* __restrict__ Qh, const short* __restrict__ Ql,
        const short* __restrict__ Kh, const short* __restrict__ Kl,
        const short* __restrict__ Vt,
        float* __restrict__ ml,
        float* __restrict__ attn,
        short* __restrict__ AO)
{
    constexpr int LSTR = 72;                 // 64 + 8 pad
    // PASS1: Q staged through kbuf (exactly 128*LSTR shorts); no qbuf.
    __shared__ short qbuf[(PASS==2) ? 128*LSTR : 8];
    __shared__ short kbuf[64*LSTR*2];        // hi | lo
    __shared__ short vbuf[(PASS==2) ? 64*LSTR : 8];
    constexpr int KOFF = 64*LSTR;

    const int tid = threadIdx.x;
    const int l = tid & 63, w = tid >> 6;
    const int lrow = l & 15, lq = l >> 4;
    const int z = blockIdx.y, b = z >> 4, h = z & 15;
    const int i0 = blockIdx.x*128;
    const size_t qrow0 = (size_t)(b*SQ + i0);
    const size_t zbase = (size_t)z*SQ*SQ;

    const int rs = tid >> 1, kh0 = (tid & 1)*32;
    short* qstage = (PASS == 2) ? (short*)qbuf : (short*)kbuf;
    bf16x8 aH[2][2], aL[2][2];
    {
        const short* qh = Qh + (qrow0 + rs)*EMB + h*HD + kh0;
        #pragma unroll
        for (int u = 0; u < 4; ++u)
            *(bf16x8*)(qstage + rs*LSTR + kh0 + u*8) = *(const bf16x8*)(qh + u*8);
        __syncthreads();
        #pragma unroll
        for (int i = 0; i < 2; ++i)
            #pragma unroll
            for (int ks = 0; ks < 2; ++ks)
                aH[i][ks] = *(const bf16x8*)(qstage + (w*32 + i*16 + lrow)*LSTR + ks*32 + lq*8);
        __syncthreads();
        const short* ql = Ql + (qrow0 + rs)*EMB + h*HD + kh0;
        #pragma unroll
        for (int u = 0; u < 4; ++u)
            *(bf16x8*)(qstage + rs*LSTR + kh0 + u*8) = *(const bf16x8*)(ql + u*8);
        __syncthreads();
        #pragma unroll
        for (int i = 0; i < 2; ++i)
            #pragma unroll
            for (int ks = 0; ks < 2; ++ks)
                aL[i][ks] = *(const bf16x8*)(qstage + (w*32 + i*16 + lrow)*LSTR + ks*32 + lq*8);
    }

    // PASS1: running (m2, l) in exp2 domain.  PASS2: M = m2 + log2(l).
    float m_st[2][4], l_st[2][4];
    #pragma unroll
    for (int i = 0; i < 2; ++i)
        #pragma unroll
        for (int rr = 0; rr < 4; ++rr) {
            if constexpr (PASS == 1) {
                m_st[i][rr] = -INFINITY; l_st[i][rr] = 0.f;
            } else {
                int row = i0 + w*32 + i*16 + lq*4 + rr;
                m_st[i][rr] = ml[(size_t)z*SQ + row];
            }
        }

    f32x4 oa[2][4] = {};

    for (int j0 = 0; j0 < SQ; j0 += 64) {
        int c = tid >> 2, kh2 = (tid & 3)*16;
        const short* khp = Kh + (size_t)(b*SQ + j0 + c)*EMB + h*HD + kh2;
        const short* klp = Kl + (size_t)(b*SQ + j0 + c)*EMB + h*HD + kh2;
        bf16x8 k0a = *(const bf16x8*)khp;
        bf16x8 k0b = *(const bf16x8*)(khp + 8);
        bf16x8 k1a = *(const bf16x8*)klp;
        bf16x8 k1b = *(const bf16x8*)(klp + 8);
        bf16x8 va{}, vb{};
        if constexpr (PASS == 2) {
            const short* vp = Vt + ((size_t)z*HD + c)*SQ + j0 + kh2;
            va = *(const bf16x8*)vp;
            vb = *(const bf16x8*)(vp + 8);
        }
        __syncthreads();
        *(bf16x8*)(kbuf + c*LSTR + kh2)            = k0a;
        *(bf16x8*)(kbuf + c*LSTR + kh2 + 8)        = k0b;
        *(bf16x8*)(kbuf + KOFF + c*LSTR + kh2)     = k1a;
        *(bf16x8*)(kbuf + KOFF + c*LSTR + kh2 + 8) = k1b;
        if constexpr (PASS == 2) {
            *(bf16x8*)(vbuf + c*LSTR + kh2)     = va;
            *(bf16x8*)(vbuf + c*LSTR + kh2 + 8) = vb;
        }
        __syncthreads();

        f32x4 acc[2][4] = {};
        #pragma unroll
        for (int ks = 0; ks < 2; ++ks) {
            bf16x8 bH[4], bL[4];
            #pragma unroll
            for (int jj = 0; jj < 4; ++jj) {
                bH[jj] = *(const bf16x8*)(kbuf + (jj*16 + lrow)*LSTR + ks*32 + lq*8);
                bL[jj] = *(const bf16x8*)(kbuf + KOFF + (jj*16 + lrow)*LSTR + ks*32 + lq*8);
            }
            #pragma unroll
            for (int i = 0; i < 2; ++i)
                #pragma unroll
                for (int jj = 0; jj < 4; ++jj) {
                    acc[i][jj] = __builtin_amdgcn_mfma_f32_16x16x32_bf16(aH[i][ks], bH[jj], acc[i][jj], 0, 0, 0);
                    acc[i][jj] = __builtin_amdgcn_mfma_f32_16x16x32_bf16(aH[i][ks], bL[jj], acc[i][jj], 0, 0, 0);
                    acc[i][jj] = __builtin_amdgcn_mfma_f32_16x16x32_bf16(aL[i][ks], bH[jj], acc[i][jj], 0, 0, 0);
                }
        }

        #pragma unroll
        for (int i = 0; i < 2; ++i)
            #pragma unroll
            for (int rr = 0; rr < 4; ++rr) {
                if constexpr (PASS == 1) {
                    float s0 = acc[i][0][rr];
                    float s1 = acc[i][1][rr];
                    float s2 = acc[i][2][rr];
                    float s3 = acc[i][3][rr];
                    float tm = fmaxf(fmaxf(s0, s1), fmaxf(s2, s3));
                    float mo = m_st[i][rr];
                    float mn = fmaxf(mo, tm);
                    l_st[i][rr] = l_st[i][rr]*exp2f(mo - mn)
                                + exp2f(s0 - mn) + exp2f(s1 - mn)
                                + exp2f(s2 - mn) + exp2f(s3 - mn);
                    m_st[i][rr] = mn;
                } else {
                    #pragma unroll
                    for (int jj = 0; jj < 4; ++jj) {
                        float p = exp2f(acc[i][jj][rr] - m_st[i][rr]);
                        qbuf[(w*32 + i*16 + lq*4 + rr)*LSTR + jj*16 + lrow] = f2bf(p);
                    }
                }
            }

        if constexpr (PASS == 2) {
            // wave-private: write the wave's 32x64 P tile to attn, coalesced
            #pragma unroll
            for (int ri = 0; ri < 8; ++ri) {
                int rl = w*32 + ri*4 + lq;
                const short* src = qbuf + rl*LSTR + lrow*4;
                short4 p4 = *(const short4*)src;
                f32x4 f;
                f[0] = bf2f(p4.x); f[1] = bf2f(p4.y);
                f[2] = bf2f(p4.z); f[3] = bf2f(p4.w);
                __builtin_nontemporal_store(f,
                    (f32x4*)(attn + zbase + (size_t)(i0 + rl)*SQ + j0 + lrow*4));
            }
            // P*V (qbuf rows wave-private)
            #pragma unroll
            for (int ks = 0; ks < 2; ++ks) {
                bf16x8 ap[2], bv[4];
                #pragma unroll
                for (int i = 0; i < 2; ++i)
                    ap[i] = *(const bf16x8*)(qbuf + (w*32 + i*16 + lrow)*LSTR + ks*32 + lq*8);
                #pragma unroll
                for (int nd = 0; nd < 4; ++nd)
                    bv[nd] = *(const bf16x8*)(vbuf + (nd*16 + lrow)*LSTR + ks*32 + lq*8);
                #pragma unroll
                for (int i = 0; i < 2; ++i)
                    #pragma unroll
                    for (int nd = 0; nd < 4; ++nd)
                        oa[i][nd] = __builtin_amdgcn_mfma_f32_16x16x32_bf16(ap[i], bv[nd], oa[i][nd], 0, 0, 0);
            }
        }
    }

    if constexpr (PASS == 1) {
        #pragma unroll
        for (int i = 0; i < 2; ++i)
            #pragma unroll
            for (int rr = 0; rr < 4; ++rr) {
                float m = m_st[i][rr], lv = l_st[i][rr];
                #pragma unroll
                for (int off = 1; off < 16; off <<= 1) {
                    float m2 = __shfl_xor(m, off);
                    float l2 = __shfl_xor(lv, off);
                    float mn = fmaxf(m, m2);
                    lv = lv*exp2f(m - mn) + l2*exp2f(m2 - mn);
                    m = mn;
                }
                if (lrow == 0) {
                    int row = i0 + w*32 + i*16 + lq*4 + rr;
                    ml[(size_t)z*SQ + row] = m + log2f(lv);
                }
            }
    } else {
        #pragma unroll
        for (int i = 0; i < 2; ++i)
            #pragma unroll
            for (int rr = 0; rr < 4; ++rr) {
                int row = i0 + w*32 + i*16 + lq*4 + rr;
                #pragma unroll
                for (int nd = 0; nd < 4; ++nd)
                    AO[(size_t)(b*SQ + row)*EMB + h*HD + nd*16 + lrow] = f2bf(oa[i][nd][rr]);
            }
    }
}

// ---------------------------------------------------------------------------
extern "C" void kernel_launch(void* const* d_in, const int* in_sizes, int n_in,
                              void* d_out, int out_size, void* d_ws, size_t ws_size,
                              hipStream_t stream)
{
    const float* hs   = (const float*)d_in[0];
    const int*   q_qw = (const int*)  d_in[1];
    const float* q_sc = (const float*)d_in[2];
    const float* q_zp = (const float*)d_in[3];
    const float* q_b  = (const float*)d_in[4];
    const int*   k_qw = (const int*)  d_in[5];
    const float* k_sc = (const float*)d_in[6];
    const float* k_zp = (const float*)d_in[7];
    const float* k_b  = (const float*)d_in[8];
    const int*   v_qw = (const int*)  d_in[9];
    const float* v_sc = (const float*)d_in[10];
    const float* v_zp = (const float*)d_in[11];
    const float* v_b  = (const float*)d_in[12];
    const int*   o_qw = (const int*)  d_in[13];
    const float* o_sc = (const float*)d_in[14];
    const float* o_zp = (const float*)d_in[15];
    const float* o_b  = (const float*)d_in[16];

    float* out  = (float*)d_out;
    float* attn = out + OUT0;

    // ws layout (60.5 MB <= 64 MB):
    //   ml | Wh: 4MW | Wl: 2MW (q,k) | Xh (->AO) | Xl (->Vt) | Qh | Ql | Kh | Kl
    const size_t WSZ = (size_t)EMB*EMB;
    const size_t TSZ = (size_t)BSQ*EMB;
    float* ml = (float*)d_ws;
    short* Wh = (short*)(ml + 2*(size_t)NB*NH*SQ);
    short* Wl = Wh + 4*WSZ;
    short* Xh = Wl + 2*WSZ;
    short* Xl = Xh + TSZ;
    short* Qh = Xl + TSZ;
    short* Ql = Qh + TSZ;
    short* Kh = Ql + TSZ;
    short* Kl = Kh + TSZ;
    short* Vt = Xl;   // overlay: Xl dead after K projection
    short* AO = Xh;   // overlay: Xh dead after V projection

    dim3 blk(256);

    k_prep<<<dim3(512, 1, 8), blk, 0, stream>>>(
        hs,
        q_qw, q_sc, q_zp, k_qw, k_sc, k_zp,
        v_qw, v_sc, v_zp, o_qw, o_sc, o_zp,
        Wh, Wl, Xh, Xl);

    k_projqkv<<<dim3(8, 32, 3), blk, 0, stream>>>(
        Xh, Xl, Wh, Wl, q_b, k_b, v_b, Qh, Ql, Kh, Kl, Vt);

    k_attn<1><<<dim3(16, 32), blk, 0, stream>>>(Qh, Ql, Kh, Kl, nullptr, ml, nullptr, nullptr);
    k_attn<2><<<dim3(16, 32), blk, 0, stream>>>(Qh, Ql, Kh, Kl, Vt, ml, attn, AO);

    k_projo<<<dim3(8, 32), blk, 0, stream>>>(AO, Wh + 3*WSZ, o_b, out);
}

// Round 11
// 819.997 us; speedup vs baseline: 1.0078x; 1.0077x over previous
//
#include <hip/hip_runtime.h>
#include <math.h>

#define EMB 1024
#define NH 16
#define HD 64
#define NB 2
#define SQ 2048
#define BSQ (NB*SQ)
#define NG 16
#define OUT0 ((size_t)BSQ*EMB)

typedef __attribute__((ext_vector_type(8))) short bf16x8;
typedef __attribute__((ext_vector_type(4))) float f32x4;

#define C_LOG2E_8 0.18033688011112042f   // log2(e)/8, folded into Q projection

__device__ __forceinline__ short f2bf(float x){
    unsigned u = __float_as_uint(x);
    u += 0x7fff + ((u >> 16) & 1);     // RNE
    return (short)(u >> 16);
}
__device__ __forceinline__ float bf2f(short h){
    return __uint_as_float(((unsigned)(unsigned short)h) << 16);
}

// ---------------------------------------------------------------------------
// fused prep: z<4 -> dequant weight quadrant z (hi always, lo for q,k);
//             z>=4 -> split X quarter (z-4) into bf16 hi/lo
// ---------------------------------------------------------------------------
__global__ __launch_bounds__(256) void k_prep(
        const float* __restrict__ hs,
        const int* qq, const float* qs, const float* qz,
        const int* kq, const float* ks, const float* kz,
        const int* vq, const float* vs, const float* vz,
        const int* oq, const float* os, const float* oz,
        short* __restrict__ Wh, short* __restrict__ Wl,
        short* __restrict__ Xh, short* __restrict__ Xl)
{
    int z = blockIdx.z;
    int idx = (blockIdx.x*256 + threadIdx.x)*8;
    alignas(16) short hv[8];
    alignas(16) short lv[8];
    if (z < 4) {
        const int*   qw = z==0?qq : z==1?kq : z==2?vq : oq;
        const float* sc = z==0?qs : z==1?ks : z==2?vs : os;
        const float* zp = z==0?qz : z==1?kz : z==2?vz : oz;
        size_t base = (size_t)z*EMB*EMB;
        int4 a = *(const int4*)(qw + idx);
        int4 b = *(const int4*)(qw + idx + 4);
        int o = idx >> 10, g = (idx & 1023) >> 6;
        float s = sc[o*NG + g], zv = zp[o*NG + g];
        int qv[8] = {a.x,a.y,a.z,a.w,b.x,b.y,b.z,b.w};
        #pragma unroll
        for (int j = 0; j < 8; ++j) {
            float wv = ((float)qv[j] - zv)*s;
            short h = f2bf(wv); hv[j] = h;
            lv[j] = f2bf(wv - bf2f(h));
        }
        *(bf16x8*)(Wh + base + idx) = *(const bf16x8*)hv;
        if (z < 2)
            *(bf16x8*)(Wl + base + idx) = *(const bf16x8*)lv;
    } else {
        size_t off = (size_t)(z - 4)*((size_t)BSQ/4*EMB) + idx;
        float4 a = *(const float4*)(hs + off);
        float4 b = *(const float4*)(hs + off + 4);
        float xv[8] = {a.x,a.y,a.z,a.w,b.x,b.y,b.z,b.w};
        #pragma unroll
        for (int j = 0; j < 8; ++j) {
            short h = f2bf(xv[j]); hv[j] = h;
            lv[j] = f2bf(xv[j] - bf2f(h));
        }
        *(bf16x8*)(Xh + off) = *(const bf16x8*)hv;
        *(bf16x8*)(Xl + off) = *(const bf16x8*)lv;
    }
}

// ---------------------------------------------------------------------------
// bf16 MFMA GEMM body: C[4096,1024] = A[4096,1024] * B[1024,1024]^T + bias
// TERMS=3: hh+hl+lh split.  TERMS=1: plain bf16.
// EPI: 0 = bf16 hi/lo pair (scaled by oscale); 2 = fp32 (nt);
//      3 = transposed bf16 -> Vt[z][d][s]
// 128x128 tile, BK=32, 4 waves (2x2).
// ---------------------------------------------------------------------------
template<int TERMS, int EPI>
__device__ __forceinline__ void proj_body(
        const short* __restrict__ Ahg, const short* __restrict__ Alg,
        const short* __restrict__ Bhg, const short* __restrict__ Blg,
        const float* __restrict__ bias,
        short* __restrict__ outH, short* __restrict__ outL,
        float* __restrict__ outF,
        int bx, int by, float oscale)
{
    constexpr bool SPL = (TERMS > 1);
    constexpr int LSTR = 40;
    constexpr int MSZ  = 128*LSTR*(SPL?2:1);
    constexpr int STAGE = 2*MSZ;
    constexpr int TSH  = (EPI == 3) ? 128*136 : 0;
    constexpr int LDSN = (STAGE > TSH) ? STAGE : TSH;
    __shared__ short lds[LDSN];
    short* As  = lds;
    short* Bs  = lds + MSZ;
    short* Asl = As + 128*LSTR;
    short* Bsl = Bs + 128*LSTR;

    const int tid = threadIdx.x;
    const int l = tid & 63, w = tid >> 6;
    const int lrow = l & 15, lq = l >> 4;
    const int wr = w >> 1, wc = w & 1;
    const int m0 = by*128, n0 = bx*128;
    const int r = tid >> 1, kh = (tid & 1)*16;

    f32x4 acc[4][4] = {};

    for (int k0 = 0; k0 < EMB; k0 += 32) {
        const short* as = Ahg + (size_t)(m0 + r)*EMB + k0 + kh;
        bf16x8 a0 = *(const bf16x8*)as;
        bf16x8 a1 = *(const bf16x8*)(as + 8);
        const short* bs = Bhg + (size_t)(n0 + r)*EMB + k0 + kh;
        bf16x8 b0 = *(const bf16x8*)bs;
        bf16x8 b1 = *(const bf16x8*)(bs + 8);
        bf16x8 a2{}, a3{}, b2{}, b3{};
        if constexpr (SPL) {
            const short* as2 = Alg + (size_t)(m0 + r)*EMB + k0 + kh;
            a2 = *(const bf16x8*)as2; a3 = *(const bf16x8*)(as2 + 8);
            const short* bs2 = Blg + (size_t)(n0 + r)*EMB + k0 + kh;
            b2 = *(const bf16x8*)bs2; b3 = *(const bf16x8*)(bs2 + 8);
        }
        __syncthreads();
        *(bf16x8*)(As + r*LSTR + kh)     = a0;
        *(bf16x8*)(As + r*LSTR + kh + 8) = a1;
        *(bf16x8*)(Bs + r*LSTR + kh)     = b0;
        *(bf16x8*)(Bs + r*LSTR + kh + 8) = b1;
        if constexpr (SPL) {
            *(bf16x8*)(Asl + r*LSTR + kh)     = a2;
            *(bf16x8*)(Asl + r*LSTR + kh + 8) = a3;
            *(bf16x8*)(Bsl + r*LSTR + kh)     = b2;
            *(bf16x8*)(Bsl + r*LSTR + kh + 8) = b3;
        }
        __syncthreads();

        bf16x8 aH[4], aL[4], bH[4], bL[4];
        #pragma unroll
        for (int i = 0; i < 4; ++i) {
            aH[i] = *(const bf16x8*)(As + (wr*64 + i*16 + lrow)*LSTR + lq*8);
            if constexpr (SPL) aL[i] = *(const bf16x8*)(Asl + (wr*64 + i*16 + lrow)*LSTR + lq*8);
        }
        #pragma unroll
        for (int j = 0; j < 4; ++j) {
            bH[j] = *(const bf16x8*)(Bs + (wc*64 + j*16 + lrow)*LSTR + lq*8);
            if constexpr (SPL) bL[j] = *(const bf16x8*)(Bsl + (wc*64 + j*16 + lrow)*LSTR + lq*8);
        }
        #pragma unroll
        for (int i = 0; i < 4; ++i)
            #pragma unroll
            for (int j = 0; j < 4; ++j) {
                acc[i][j] = __builtin_amdgcn_mfma_f32_16x16x32_bf16(aH[i], bH[j], acc[i][j], 0, 0, 0);
                if constexpr (SPL) {
                    acc[i][j] = __builtin_amdgcn_mfma_f32_16x16x32_bf16(aH[i], bL[j], acc[i][j], 0, 0, 0);
                    acc[i][j] = __builtin_amdgcn_mfma_f32_16x16x32_bf16(aL[i], bH[j], acc[i][j], 0, 0, 0);
                }
            }
    }

    if constexpr (EPI == 3) {
        // transpose through LDS, write Vt[z][d][s] coalesced along s
        __syncthreads();
        #pragma unroll
        for (int i = 0; i < 4; ++i) {
            int rl = wr*64 + i*16 + lq*4;
            #pragma unroll
            for (int j = 0; j < 4; ++j) {
                int cl = wc*64 + j*16 + lrow;
                float bv = bias[n0 + cl];
                #pragma unroll
                for (int rr = 0; rr < 4; ++rr)
                    lds[cl*136 + rl + rr] = f2bf(acc[i][j][rr] + bv);
            }
        }
        __syncthreads();
        int c = tid >> 1, hf = (tid & 1)*64;
        int gc = n0 + c;
        int z2 = (m0 >> 11)*16 + (gc >> 6);
        int d = gc & 63;
        short* dst = outH + ((size_t)z2*HD + d)*SQ + (m0 & (SQ-1)) + hf;
        #pragma unroll
        for (int u = 0; u < 8; ++u)
            *(bf16x8*)(dst + u*8) = *(const bf16x8*)(lds + c*136 + hf + u*8);
        return;
    }

    #pragma unroll
    for (int i = 0; i < 4; ++i) {
        int rb = m0 + wr*64 + i*16 + lq*4;
        #pragma unroll
        for (int j = 0; j < 4; ++j) {
            int cb = n0 + wc*64 + j*16 + lrow;
            float bv = bias[cb];
            #pragma unroll
            for (int rr = 0; rr < 4; ++rr) {
                float y = acc[i][j][rr] + bv;
                size_t off = (size_t)(rb + rr)*EMB + cb;
                if constexpr (EPI == 0) {
                    y *= oscale;
                    short hh = f2bf(y);
                    outH[off] = hh;
                    outL[off] = f2bf(y - bf2f(hh));
                } else {
                    __builtin_nontemporal_store(y, outF + off);
                }
            }
        }
    }
}

// Q (scaled by log2(e)/8), K (3-term, hi/lo out), V (1-term, transposed) via grid.z
__global__ __launch_bounds__(256, 2) void k_projqkv(
        const short* __restrict__ Xh, const short* __restrict__ Xl,
        const short* __restrict__ Wh, const short* __restrict__ Wl,
        const float* bq, const float* bk, const float* bv,
        short* Qh, short* Ql, short* Kh, short* Kl, short* Vt)
{
    const size_t WSZ = (size_t)EMB*EMB;
    int z = blockIdx.z;
    if (z < 2)
        proj_body<3,0>(Xh, Xl, Wh + (size_t)z*WSZ, Wl + (size_t)z*WSZ,
                       z ? bk : bq, z ? Kh : Qh, z ? Kl : Ql, nullptr,
                       blockIdx.x, blockIdx.y, z ? 1.0f : C_LOG2E_8);
    else
        proj_body<1,3>(Xh, nullptr, Wh + 2*WSZ, nullptr, bv, Vt, nullptr, nullptr,
                       blockIdx.x, blockIdx.y, 1.0f);
}

__global__ __launch_bounds__(256, 2) void k_projo(
        const short* __restrict__ AO, const short* __restrict__ Wh,
        const float* bo, float* out)
{
    proj_body<1,2>(AO, nullptr, Wh, nullptr, bo, nullptr, nullptr, out,
                   blockIdx.x, blockIdx.y, 1.0f);
}

// ---------------------------------------------------------------------------
// attention, two passes over an identical score computation (R8 structure).
// Q pre-scaled by log2(e)/8 => score is acc directly; exp via exp2f.
// PASS1: lane-local online (m,l), butterfly merge, store m and l.
// PASS2: p = exp2(acc - m) * (1/l); P (bf16) -> LDS -> coalesced fp32 attn
//        write + P*V.  Q staged hi then lo through ONE 128xLSTR buffer.
// ---------------------------------------------------------------------------
template<int PASS>
__global__ __launch_bounds__(256, (PASS==1) ? 3 : 2) void k_attn(
        const short* __restrict__ Qh, const short* __restrict__ Ql,
        const short* __restrict__ Kh, const short* __restrict__ Kl,
        const short* __restrict__ Vt,
        float* __restrict__ ml,
        float* __restrict__ attn,
        short* __restrict__ AO)
{
    constexpr int LSTR = 72;                 // 64 + 8 pad
    __shared__ short qbuf[128*LSTR];         // Q hi then lo staging; P tile in PASS2
    __shared__ short kbuf[64*LSTR*2];        // hi | lo
    __shared__ short vbuf[(PASS==2) ? 64*LSTR : 8];
    constexpr int KOFF = 64*LSTR;

    const int tid = threadIdx.x;
    const int l = tid & 63, w = tid >> 6;
    const int lrow = l & 15, lq = l >> 4;
    const int z = blockIdx.y, b = z >> 4, h = z & 15;
    const int i0 = blockIdx.x*128;
    const size_t qrow0 = (size_t)(b*SQ + i0);
    const size_t zbase = (size_t)z*SQ*SQ;

    const int rs = tid >> 1, kh0 = (tid & 1)*32;
    bf16x8 aH[2][2], aL[2][2];
    {
        const short* qh = Qh + (qrow0 + rs)*EMB + h*HD + kh0;
        #pragma unroll
        for (int u = 0; u < 4; ++u)
            *(bf16x8*)(qbuf + rs*LSTR + kh0 + u*8) = *(const bf16x8*)(qh + u*8);
        __syncthreads();
        #pragma unroll
        for (int i = 0; i < 2; ++i)
            #pragma unroll
            for (int ks = 0; ks < 2; ++ks)
                aH[i][ks] = *(const bf16x8*)(qbuf + (w*32 + i*16 + lrow)*LSTR + ks*32 + lq*8);
        __syncthreads();
        const short* ql = Ql + (qrow0 + rs)*EMB + h*HD + kh0;
        #pragma unroll
        for (int u = 0; u < 4; ++u)
            *(bf16x8*)(qbuf + rs*LSTR + kh0 + u*8) = *(const bf16x8*)(ql + u*8);
        __syncthreads();
        #pragma unroll
        for (int i = 0; i < 2; ++i)
            #pragma unroll
            for (int ks = 0; ks < 2; ++ks)
                aL[i][ks] = *(const bf16x8*)(qbuf + (w*32 + i*16 + lrow)*LSTR + ks*32 + lq*8);
    }

    float m_st[2][4], l_st[2][4];
    #pragma unroll
    for (int i = 0; i < 2; ++i)
        #pragma unroll
        for (int rr = 0; rr < 4; ++rr) {
            if constexpr (PASS == 1) {
                m_st[i][rr] = -INFINITY; l_st[i][rr] = 0.f;
            } else {
                int row = i0 + w*32 + i*16 + lq*4 + rr;
                m_st[i][rr] = ml[(size_t)z*SQ + row];
                l_st[i][rr] = 1.0f / ml[(size_t)NB*NH*SQ + (size_t)z*SQ + row];
            }
        }

    f32x4 oa[2][4] = {};

    for (int j0 = 0; j0 < SQ; j0 += 64) {
        int c = tid >> 2, kh2 = (tid & 3)*16;
        const short* khp = Kh + (size_t)(b*SQ + j0 + c)*EMB + h*HD + kh2;
        const short* klp = Kl + (size_t)(b*SQ + j0 + c)*EMB + h*HD + kh2;
        bf16x8 k0a = *(const bf16x8*)khp;
        bf16x8 k0b = *(const bf16x8*)(khp + 8);
        bf16x8 k1a = *(const bf16x8*)klp;
        bf16x8 k1b = *(const bf16x8*)(klp + 8);
        bf16x8 va{}, vb{};
        if constexpr (PASS == 2) {
            const short* vp = Vt + ((size_t)z*HD + c)*SQ + j0 + kh2;
            va = *(const bf16x8*)vp;
            vb = *(const bf16x8*)(vp + 8);
        }
        __syncthreads();
        *(bf16x8*)(kbuf + c*LSTR + kh2)            = k0a;
        *(bf16x8*)(kbuf + c*LSTR + kh2 + 8)        = k0b;
        *(bf16x8*)(kbuf + KOFF + c*LSTR + kh2)     = k1a;
        *(bf16x8*)(kbuf + KOFF + c*LSTR + kh2 + 8) = k1b;
        if constexpr (PASS == 2) {
            *(bf16x8*)(vbuf + c*LSTR + kh2)     = va;
            *(bf16x8*)(vbuf + c*LSTR + kh2 + 8) = vb;
        }
        __syncthreads();

        f32x4 acc[2][4] = {};
        #pragma unroll
        for (int ks = 0; ks < 2; ++ks) {
            bf16x8 bH[4], bL[4];
            #pragma unroll
            for (int jj = 0; jj < 4; ++jj) {
                bH[jj] = *(const bf16x8*)(kbuf + (jj*16 + lrow)*LSTR + ks*32 + lq*8);
                bL[jj] = *(const bf16x8*)(kbuf + KOFF + (jj*16 + lrow)*LSTR + ks*32 + lq*8);
            }
            #pragma unroll
            for (int i = 0; i < 2; ++i)
                #pragma unroll
                for (int jj = 0; jj < 4; ++jj) {
                    acc[i][jj] = __builtin_amdgcn_mfma_f32_16x16x32_bf16(aH[i][ks], bH[jj], acc[i][jj], 0, 0, 0);
                    acc[i][jj] = __builtin_amdgcn_mfma_f32_16x16x32_bf16(aH[i][ks], bL[jj], acc[i][jj], 0, 0, 0);
                    acc[i][jj] = __builtin_amdgcn_mfma_f32_16x16x32_bf16(aL[i][ks], bH[jj], acc[i][jj], 0, 0, 0);
                }
        }

        #pragma unroll
        for (int i = 0; i < 2; ++i)
            #pragma unroll
            for (int rr = 0; rr < 4; ++rr) {
                if constexpr (PASS == 1) {
                    float s0 = acc[i][0][rr];
                    float s1 = acc[i][1][rr];
                    float s2 = acc[i][2][rr];
                    float s3 = acc[i][3][rr];
                    float tm = fmaxf(fmaxf(s0, s1), fmaxf(s2, s3));
                    float mo = m_st[i][rr];
                    float mn = fmaxf(mo, tm);
                    l_st[i][rr] = l_st[i][rr]*exp2f(mo - mn)
                                + exp2f(s0 - mn) + exp2f(s1 - mn)
                                + exp2f(s2 - mn) + exp2f(s3 - mn);
                    m_st[i][rr] = mn;
                } else {
                    #pragma unroll
                    for (int jj = 0; jj < 4; ++jj) {
                        float p = exp2f(acc[i][jj][rr] - m_st[i][rr]) * l_st[i][rr];
                        qbuf[(w*32 + i*16 + lq*4 + rr)*LSTR + jj*16 + lrow] = f2bf(p);
                    }
                }
            }

        if constexpr (PASS == 2) {
            // wave-private: write the wave's 32x64 P tile to attn, coalesced
            #pragma unroll
            for (int ri = 0; ri < 8; ++ri) {
                int rl = w*32 + ri*4 + lq;
                const short* src = qbuf + rl*LSTR + lrow*4;
                short4 p4 = *(const short4*)src;
                f32x4 f;
                f[0] = bf2f(p4.x); f[1] = bf2f(p4.y);
                f[2] = bf2f(p4.z); f[3] = bf2f(p4.w);
                __builtin_nontemporal_store(f,
                    (f32x4*)(attn + zbase + (size_t)(i0 + rl)*SQ + j0 + lrow*4));
            }
            // P*V (qbuf rows wave-private)
            #pragma unroll
            for (int ks = 0; ks < 2; ++ks) {
                bf16x8 ap[2], bv[4];
                #pragma unroll
                for (int i = 0; i < 2; ++i)
                    ap[i] = *(const bf16x8*)(qbuf + (w*32 + i*16 + lrow)*LSTR + ks*32 + lq*8);
                #pragma unroll
                for (int nd = 0; nd < 4; ++nd)
                    bv[nd] = *(const bf16x8*)(vbuf + (nd*16 + lrow)*LSTR + ks*32 + lq*8);
                #pragma unroll
                for (int i = 0; i < 2; ++i)
                    #pragma unroll
                    for (int nd = 0; nd < 4; ++nd)
                        oa[i][nd] = __builtin_amdgcn_mfma_f32_16x16x32_bf16(ap[i], bv[nd], oa[i][nd], 0, 0, 0);
            }
        }
    }

    if constexpr (PASS == 1) {
        #pragma unroll
        for (int i = 0; i < 2; ++i)
            #pragma unroll
            for (int rr = 0; rr < 4; ++rr) {
                float m = m_st[i][rr], lv = l_st[i][rr];
                #pragma unroll
                for (int off = 1; off < 16; off <<= 1) {
                    float m2 = __shfl_xor(m, off);
                    float l2 = __shfl_xor(lv, off);
                    float mn = fmaxf(m, m2);
                    lv = lv*exp2f(m - mn) + l2*exp2f(m2 - mn);
                    m = mn;
                }
                if (lrow == 0) {
                    int row = i0 + w*32 + i*16 + lq*4 + rr;
                    ml[(size_t)z*SQ + row] = m;
                    ml[(size_t)NB*NH*SQ + (size_t)z*SQ + row] = lv;
                }
            }
    } else {
        #pragma unroll
        for (int i = 0; i < 2; ++i)
            #pragma unroll
            for (int rr = 0; rr < 4; ++rr) {
                int row = i0 + w*32 + i*16 + lq*4 + rr;
                #pragma unroll
                for (int nd = 0; nd < 4; ++nd)
                    AO[(size_t)(b*SQ + row)*EMB + h*HD + nd*16 + lrow] = f2bf(oa[i][nd][rr]);
            }
    }
}

// ---------------------------------------------------------------------------
extern "C" void kernel_launch(void* const* d_in, const int* in_sizes, int n_in,
                              void* d_out, int out_size, void* d_ws, size_t ws_size,
                              hipStream_t stream)
{
    const float* hs   = (const float*)d_in[0];
    const int*   q_qw = (const int*)  d_in[1];
    const float* q_sc = (const float*)d_in[2];
    const float* q_zp = (const float*)d_in[3];
    const float* q_b  = (const float*)d_in[4];
    const int*   k_qw = (const int*)  d_in[5];
    const float* k_sc = (const float*)d_in[6];
    const float* k_zp = (const float*)d_in[7];
    const float* k_b  = (const float*)d_in[8];
    const int*   v_qw = (const int*)  d_in[9];
    const float* v_sc = (const float*)d_in[10];
    const float* v_zp = (const float*)d_in[11];
    const float* v_b  = (const float*)d_in[12];
    const int*   o_qw = (const int*)  d_in[13];
    const float* o_sc = (const float*)d_in[14];
    const float* o_zp = (const float*)d_in[15];
    const float* o_b  = (const float*)d_in[16];

    float* out  = (float*)d_out;
    float* attn = out + OUT0;

    // ws layout (60.5 MB <= 64 MB):
    //   ml | Wh: 4MW | Wl: 2MW (q,k) | Xh (->AO) | Xl (->Vt) | Qh | Ql | Kh | Kl
    const size_t WSZ = (size_t)EMB*EMB;
    const size_t TSZ = (size_t)BSQ*EMB;
    float* ml = (float*)d_ws;
    short* Wh = (short*)(ml + 2*(size_t)NB*NH*SQ);
    short* Wl = Wh + 4*WSZ;
    short* Xh = Wl + 2*WSZ;
    short* Xl = Xh + TSZ;
    short* Qh = Xl + TSZ;
    short* Ql = Qh + TSZ;
    short* Kh = Ql + TSZ;
    short* Kl = Kh + TSZ;
    short* Vt = Xl;   // overlay: Xl dead after K projection
    short* AO = Xh;   // overlay: Xh dead after V projection

    dim3 blk(256);

    k_prep<<<dim3(512, 1, 8), blk, 0, stream>>>(
        hs,
        q_qw, q_sc, q_zp, k_qw, k_sc, k_zp,
        v_qw, v_sc, v_zp, o_qw, o_sc, o_zp,
        Wh, Wl, Xh, Xl);

    k_projqkv<<<dim3(8, 32, 3), blk, 0, stream>>>(
        Xh, Xl, Wh, Wl, q_b, k_b, v_b, Qh, Ql, Kh, Kl, Vt);

    k_attn<1><<<dim3(16, 32), blk, 0, stream>>>(Qh, Ql, Kh, Kl, nullptr, ml, nullptr, nullptr);
    k_attn<2><<<dim3(16, 32), blk, 0, stream>>>(Qh, Ql, Kh, Kl, Vt, ml, attn, AO);

    k_projo<<<dim3(8, 32), blk, 0, stream>>>(AO, Wh + 3*WSZ, o_b, out);
}